// Round 6
// baseline (465.350 us; speedup 1.0000x reference)
//
#include <hip/hip_runtime.h>

// SNN fused kernel for MI355X (gfx950) — round 5: wave-autonomous, barrier-free.
//
//  Numerics IDENTICAL to round 4 (passed, absmax 0.0215):
//   - V = rne(x*2^27); V' = V + 2^30 >= 0; bytes of (V'^0x80808080) are exact
//     signed digits of (V - 1082163328); constant folded into bias_eff.
//   - w1/w2 quantized at 2^34 / 2^33, balanced signed 8-bit digits.
//   - Digit-pair products accumulate EXACTLY in i32 MFMA accs; classes s=2..6
//     combined in fp64 (s<2 dropped, <5e-10). LIF recurrences fp64.
//   - Layer 3 closed form: out = (w3 . sum_t c_t*spk2_t + b3*sum(c_t))/10.
//  Structure changes vs round 4:
//   - Wave owns 16 batch rows end-to-end (block = 64 rows, grid 2048):
//     x digit-prep no longer 4x-redundant across waves.
//   - P1 loops 4 w1-Mtiles (A-frags from global/L2, per-Mtile).
//   - Spikes: per-wave 10KB LDS region, srow = t*16 + r, dword-group swizzle
//     f(r,nt)=nt^((r>>1)&3) -> conflict-free writes AND reads.
//   - P2 M-tile = time-slice t => lane owns fixed (4 rows x 2 k2) streams;
//     LIF2 fully in registers. NO c2 buffer, ZERO barriers.
//   - LDS exactly 40960B -> 4 blocks/CU; __launch_bounds__(256,4) (VGPR<=128).

#define NBLK 2048   // 2048 blocks * 64 rows = 131072

typedef __attribute__((ext_vector_type(4))) int i32x4;

__device__ __forceinline__ unsigned prm(unsigned hi, unsigned lo, unsigned sel) {
    return __builtin_amdgcn_perm(hi, lo, sel);
}

// ---------------- prep: identical to round 4 ----------------
// i8 16x16x64 frags: lane l -> (row|col) = l&15, k = (l>>4)*16 + e, e = byte 0..15.
// ws bytes: w1 A-frags [((nt*2+kt)*4+p)*1024], w2 B-frags at +32768, bias_eff f64[64] at +40960.
__global__ void snn_prep(const float* __restrict__ w1, const float* __restrict__ b1,
                         const float* __restrict__ w2, unsigned char* __restrict__ wsb) {
    int tid = threadIdx.x;
    // w1: [64][128] scale 2^34 -> A-frags (A[m=neuron][k=input])
    for (int it = tid; it < 8192; it += 256) {
        int n = it >> 7, k = it & 127;
        int V = (int)llround((double)w1[n * 128 + k] * 0x1p34);
        int nt = n >> 4, m = n & 15, kt = k >> 6, kgp = (k >> 4) & 3, e = k & 15;
        unsigned base = (unsigned)(((nt * 2 + kt) * 4) << 10) + (unsigned)(((kgp << 4) | m) * 16 + e);
#pragma unroll
        for (int p = 0; p < 4; ++p) {
            int d = ((V + 128) & 255) - 128; V = (V - d) >> 8;
            wsb[base + ((unsigned)p << 10)] = (unsigned char)d;
        }
    }
    // w2: [32][64] scale 2^33 -> B-frags (B[k=L1 neuron][n=L2 neuron])
    for (int it = tid; it < 2048; it += 256) {
        int n = it >> 6, k = it & 63;
        int V = (int)llround((double)w2[n * 64 + k] * 0x1p33);
        int nt2 = n >> 4, c = n & 15, kgp = k >> 4, e = k & 15;
        unsigned base = 32768u + (unsigned)((nt2 * 4) << 10) + (unsigned)(((kgp << 4) | c) * 16 + e);
#pragma unroll
        for (int p = 0; p < 4; ++p) {
            int d = ((V + 128) & 255) - 128; V = (V - d) >> 8;
            wsb[base + ((unsigned)p << 10)] = (unsigned char)d;
        }
    }
    // bias_eff[n] = b1[n] + 1082163328 * sum_k Vw1[n][k] * 2^-61
    if (tid < 64) {
        long long s = 0;
        for (int k = 0; k < 128; ++k) s += llround((double)w1[tid * 128 + k] * 0x1p34);
        double* biasd = (double*)(wsb + 40960);
        biasd[tid] = (double)b1[tid] + 1082163328.0 * (double)s * 0x1p-61;
    }
}

// ---------------- main fused kernel ----------------
__global__ __launch_bounds__(256, 4) void snn_main(
    const float* __restrict__ x,
    const float* __restrict__ b2,
    const float* __restrict__ w3,
    const float* __restrict__ b3,
    const unsigned char* __restrict__ wsb,
    float* __restrict__ out)
{
    // per-wave spike region: 160 srows (srow = t*16 + r) x 64 i8 = 10240B; total 40960B
    __shared__ __align__(16) unsigned char sS[4][10240];

    const int tid  = threadIdx.x;
    const int wave = tid >> 6;
    const int lane = tid & 63;
    const int m15  = lane & 15;      // P1: batch row; P2: A-row (srow) & k2 col
    const int kg   = lane >> 4;      // P1: k-group / neuron sub-block; P2: k-strip / out-row group
    const int swz  = (m15 >> 1) & 3; // dword-group bank swizzle key
    unsigned char* sw = sS[wave];
    const int r0 = blockIdx.x * 64 + wave * 16;   // this wave's first batch row

    // ---- x digit B-frags for this wave's 16 rows (same math as round 4) ----
    i32x4 bx[2][4];
#pragma unroll
    for (int kt = 0; kt < 2; ++kt) {
        const float4* xp = (const float4*)(x + (size_t)(r0 + m15) * 128 + kt * 64 + kg * 16);
        float4 q0 = xp[0], q1 = xp[1], q2 = xp[2], q3 = xp[3];
        unsigned o0[4], o1[4], o2[4], o3[4];
#pragma unroll
        for (int g = 0; g < 4; ++g) {
            float f0 = (g == 0 ? q0.x : g == 1 ? q1.x : g == 2 ? q2.x : q3.x);
            float f1 = (g == 0 ? q0.y : g == 1 ? q1.y : g == 2 ? q2.y : q3.y);
            float f2 = (g == 0 ? q0.z : g == 1 ? q1.z : g == 2 ? q2.z : q3.z);
            float f3 = (g == 0 ? q0.w : g == 1 ? q1.w : g == 2 ? q2.w : q3.w);
            unsigned V0 = ((unsigned)(__float2int_rn(f0 * 0x1p27f) + 0x40000000)) ^ 0x80808080u;
            unsigned V1 = ((unsigned)(__float2int_rn(f1 * 0x1p27f) + 0x40000000)) ^ 0x80808080u;
            unsigned V2 = ((unsigned)(__float2int_rn(f2 * 0x1p27f) + 0x40000000)) ^ 0x80808080u;
            unsigned V3 = ((unsigned)(__float2int_rn(f3 * 0x1p27f) + 0x40000000)) ^ 0x80808080u;
            unsigned A01 = prm(V1, V0, 0x05010400u), A23 = prm(V3, V2, 0x05010400u);
            unsigned B01 = prm(V1, V0, 0x07030602u), B23 = prm(V3, V2, 0x07030602u);
            o0[g] = prm(A23, A01, 0x05040100u);
            o1[g] = prm(A23, A01, 0x07060302u);
            o2[g] = prm(B23, B01, 0x05040100u);
            o3[g] = prm(B23, B01, 0x07060302u);
        }
        bx[kt][0] = (i32x4){(int)o0[0], (int)o0[1], (int)o0[2], (int)o0[3]};
        bx[kt][1] = (i32x4){(int)o1[0], (int)o1[1], (int)o1[2], (int)o1[3]};
        bx[kt][2] = (i32x4){(int)o2[0], (int)o2[1], (int)o2[2], (int)o2[3]};
        bx[kt][3] = (i32x4){(int)o3[0], (int)o3[1], (int)o3[2], (int)o3[3]};
    }

    const double* biasd = (const double*)(wsb + 40960);

    // ===== P1: 4 neuron-Mtiles; exact fc1 + fp64 LIF1 + swizzled spike writes =====
#pragma unroll
    for (int nt1 = 0; nt1 < 4; ++nt1) {
        i32x4 aw[2][4];
#pragma unroll
        for (int kt = 0; kt < 2; ++kt)
#pragma unroll
            for (int p = 0; p < 4; ++p)
                aw[kt][p] = *(const i32x4*)(wsb + (unsigned)(((nt1 * 2 + kt) * 4 + p) << 10) + lane * 16);
        double be[4];
#pragma unroll
        for (int j = 0; j < 4; ++j) be[j] = biasd[nt1 * 16 + kg * 4 + j];

        i32x4 acc0 = {0,0,0,0}, acc1 = {0,0,0,0}, acc2 = {0,0,0,0}, acc3 = {0,0,0,0}, acc4 = {0,0,0,0};
#pragma unroll
        for (int kt = 0; kt < 2; ++kt) {
            // shift classes s = i(w) + j(x), s >= 2
            acc0 = __builtin_amdgcn_mfma_i32_16x16x64_i8(aw[kt][0], bx[kt][2], acc0, 0, 0, 0);
            acc0 = __builtin_amdgcn_mfma_i32_16x16x64_i8(aw[kt][1], bx[kt][1], acc0, 0, 0, 0);
            acc0 = __builtin_amdgcn_mfma_i32_16x16x64_i8(aw[kt][2], bx[kt][0], acc0, 0, 0, 0);
            acc1 = __builtin_amdgcn_mfma_i32_16x16x64_i8(aw[kt][0], bx[kt][3], acc1, 0, 0, 0);
            acc1 = __builtin_amdgcn_mfma_i32_16x16x64_i8(aw[kt][1], bx[kt][2], acc1, 0, 0, 0);
            acc1 = __builtin_amdgcn_mfma_i32_16x16x64_i8(aw[kt][2], bx[kt][1], acc1, 0, 0, 0);
            acc1 = __builtin_amdgcn_mfma_i32_16x16x64_i8(aw[kt][3], bx[kt][0], acc1, 0, 0, 0);
            acc2 = __builtin_amdgcn_mfma_i32_16x16x64_i8(aw[kt][1], bx[kt][3], acc2, 0, 0, 0);
            acc2 = __builtin_amdgcn_mfma_i32_16x16x64_i8(aw[kt][2], bx[kt][2], acc2, 0, 0, 0);
            acc2 = __builtin_amdgcn_mfma_i32_16x16x64_i8(aw[kt][3], bx[kt][1], acc2, 0, 0, 0);
            acc3 = __builtin_amdgcn_mfma_i32_16x16x64_i8(aw[kt][2], bx[kt][3], acc3, 0, 0, 0);
            acc3 = __builtin_amdgcn_mfma_i32_16x16x64_i8(aw[kt][3], bx[kt][2], acc3, 0, 0, 0);
            acc4 = __builtin_amdgcn_mfma_i32_16x16x64_i8(aw[kt][3], bx[kt][3], acc4, 0, 0, 0);
        }
        // combine classes exactly in fp64; LIF1; swizzled spike write (1 b32/step)
        double c[4], cm1[4], mem[4];
        bool rst[4];
#pragma unroll
        for (int j = 0; j < 4; ++j) {
            c[j] = be[j] + (double)acc0[j] * 0x1p-45 + (double)acc1[j] * 0x1p-37
                         + (double)acc2[j] * 0x1p-29 + (double)acc3[j] * 0x1p-21
                         + (double)acc4[j] * 0x1p-13;
            cm1[j] = c[j] - 1.0;
            mem[j] = 0.0; rst[j] = false;
        }
        const int wbase = ((nt1 ^ swz) << 4) + kg * 4;   // dword-group swizzle
#pragma unroll
        for (int t = 0; t < 10; ++t) {
            unsigned sb = 0u;
#pragma unroll
            for (int j = 0; j < 4; ++j) {
                mem[j] = __fma_rn(0.9, mem[j], rst[j] ? cm1[j] : c[j]);
                rst[j] = mem[j] > 1.0;
                sb |= rst[j] ? (1u << (8 * j)) : 0u;
            }
            *(unsigned*)(sw + (t * 16 + m15) * 64 + wbase) = sb;
        }
    }

    __builtin_amdgcn_sched_barrier(0);   // keep w2f loads out of P1's register peak

    // ---- w2 B-frags + P3 constants ----
    i32x4 w2f[2][4];
#pragma unroll
    for (int nt2 = 0; nt2 < 2; ++nt2)
#pragma unroll
        for (int p = 0; p < 4; ++p)
            w2f[nt2][p] = *(const i32x4*)(wsb + 32768u + (unsigned)((nt2 * 4 + p) << 10) + lane * 16);

    const double b2d0 = (double)b2[m15];
    const double b2d1 = (double)b2[m15 + 16];
    float w3lo[4], w3hi[4], b3c[4];
#pragma unroll
    for (int cc = 0; cc < 4; ++cc) {
        w3lo[cc] = w3[cc * 32 + m15];
        w3hi[cc] = w3[cc * 32 + m15 + 16];
        b3c[cc]  = (float)((double)b3[cc] * 41.381059609);   // b3 * sum(c_t)
    }

    // ===== P2: time-slice MFMAs + fp64 LIF2 fully in registers =====
    // lane owns rows r = 4*kg+j (j=0..3), k2 = m15 (s=0..3) and m15+16 (s=4..7)
    const float CTf[10] = {6.5132156f, 6.1257951f, 5.6953279f, 5.2170310f, 4.6855900f,
                           4.0951000f, 3.4390000f, 2.7100000f, 1.9000000f, 1.0000000f};
    double mem2[8] = {0,0,0,0,0,0,0,0};
    float  z[8]    = {0,0,0,0,0,0,0,0};
    bool   rs2[8]  = {false,false,false,false,false,false,false,false};

#pragma unroll
    for (int t = 0; t < 10; ++t) {
        i32x4 a = *(const i32x4*)(sw + (t * 16 + m15) * 64 + ((kg ^ swz) << 4));
        i32x4 p0[2] = {{0,0,0,0},{0,0,0,0}}, p1[2] = {{0,0,0,0},{0,0,0,0}};
        i32x4 p2[2] = {{0,0,0,0},{0,0,0,0}}, p3[2] = {{0,0,0,0},{0,0,0,0}};
#pragma unroll
        for (int nt2 = 0; nt2 < 2; ++nt2) {
            p0[nt2] = __builtin_amdgcn_mfma_i32_16x16x64_i8(a, w2f[nt2][0], p0[nt2], 0, 0, 0);
            p1[nt2] = __builtin_amdgcn_mfma_i32_16x16x64_i8(a, w2f[nt2][1], p1[nt2], 0, 0, 0);
            p2[nt2] = __builtin_amdgcn_mfma_i32_16x16x64_i8(a, w2f[nt2][2], p2[nt2], 0, 0, 0);
            p3[nt2] = __builtin_amdgcn_mfma_i32_16x16x64_i8(a, w2f[nt2][3], p3[nt2], 0, 0, 0);
        }
#pragma unroll
        for (int nt2 = 0; nt2 < 2; ++nt2) {
            const double b2d = nt2 ? b2d1 : b2d0;
#pragma unroll
            for (int j = 0; j < 4; ++j) {
                const int s = nt2 * 4 + j;
                int lo = p0[nt2][j] + p1[nt2][j] * 256 + p2[nt2][j] * 65536;   // exact, |lo| < 2^30
                double cv = __fma_rn((double)lo, 0x1p-33,
                            __fma_rn((double)p3[nt2][j], 0x1p-9, b2d));
                double t2 = __fma_rn(0.9, mem2[s], cv);
                mem2[s] = rs2[s] ? (t2 - 1.0) : t2;
                rs2[s] = mem2[s] > 1.0;
                z[s] += rs2[s] ? CTf[t] : 0.0f;
            }
        }
    }

    // ===== P3: fused w3 reduce (16-lane butterflies) + store =====
#pragma unroll
    for (int j = 0; j < 4; ++j) {
        float red[4];
#pragma unroll
        for (int cc = 0; cc < 4; ++cc) {
            float v = z[j] * w3lo[cc] + z[4 + j] * w3hi[cc];
            v += __shfl_xor(v, 1);
            v += __shfl_xor(v, 2);
            v += __shfl_xor(v, 4);
            v += __shfl_xor(v, 8);
            red[cc] = (v + b3c[cc]) * 0.1f;
        }
        if (m15 == 0) {
            float4 o4 = {red[0], red[1], red[2], red[3]};
            *(float4*)(out + (size_t)(r0 + kg * 4 + j) * 4) = o4;
        }
    }
}

extern "C" void kernel_launch(void* const* d_in, const int* in_sizes, int n_in,
                              void* d_out, int out_size, void* d_ws, size_t ws_size,
                              hipStream_t stream) {
    const float* x  = (const float*)d_in[0];
    const float* w1 = (const float*)d_in[1];
    const float* b1 = (const float*)d_in[2];
    const float* w2 = (const float*)d_in[3];
    const float* b2 = (const float*)d_in[4];
    const float* w3 = (const float*)d_in[5];
    const float* b3 = (const float*)d_in[6];
    unsigned char* wsb = (unsigned char*)d_ws;   // needs 41472 bytes
    float* out = (float*)d_out;

    snn_prep<<<1, 256, 0, stream>>>(w1, b1, w2, wsb);
    snn_main<<<NBLK, 256, 0, stream>>>(x, b2, w3, b3, wsb, out);
}

// Round 7
// 204.768 us; speedup vs baseline: 2.2726x; 2.2726x over previous
//
#include <hip/hip_runtime.h>

// SNN fused kernel for MI355X (gfx950) — round 6: round-5 structure, spill fixed.
//
//  Round-5 post-mortem: __launch_bounds__(256,4) capped VGPR at 64 -> ~1.4GB of
//  scratch spill traffic per dispatch (FETCH 855MB / WRITE 575MB), 465us.
//  Fix: launch_bounds(256,2) (cap 256 VGPR; LDS already limits to 4 blk/CU,
//  VGPR ~150-190 -> 2-3 blk/CU) + peak-pressure trims (sequential nt2 in P2,
//  no cached cm1). Numerics and layout IDENTICAL to rounds 4/5 (both passed
//  at absmax 0.0215).
//
//  Numerics:
//   - V = rne(x*2^27); V' = V + 2^30 >= 0; bytes of (V'^0x80808080) are exact
//     signed digits of (V - 1082163328); constant folded into bias_eff.
//   - w1/w2 quantized at 2^34 / 2^33, balanced signed 8-bit digits.
//   - Digit-pair products accumulate EXACTLY in i32 MFMA accs; classes s=2..6
//     combined in fp64 (s<2 dropped, <5e-10). LIF recurrences fp64.
//   - Layer 3 closed form: out = (w3 . sum_t c_t*spk2_t + b3*sum(c_t))/10.
//  Structure:
//   - Wave owns 16 batch rows end-to-end (block = 64 rows, grid 2048);
//     x digit-prep done once per wave (not 4x-redundant).
//   - P1 loops 4 w1-Mtiles (A-frags from global/L2 per-Mtile).
//   - Spikes: per-wave 10KB LDS region, srow = t*16 + r, dword-group swizzle
//     f(r,nt)=nt^((r>>1)&3) -> conflict-free writes AND reads.
//   - P2 M-tile = time-slice t => lane owns fixed (4 rows x 2 k2) streams;
//     LIF2 fully in registers. NO c2 buffer, ZERO __syncthreads.

#define NBLK 2048   // 2048 blocks * 64 rows = 131072

typedef __attribute__((ext_vector_type(4))) int i32x4;

__device__ __forceinline__ unsigned prm(unsigned hi, unsigned lo, unsigned sel) {
    return __builtin_amdgcn_perm(hi, lo, sel);
}

// ---------------- prep: identical to rounds 4/5 ----------------
// i8 16x16x64 frags: lane l -> (row|col) = l&15, k = (l>>4)*16 + e, e = byte 0..15.
// ws bytes: w1 A-frags [((nt*2+kt)*4+p)*1024], w2 B-frags at +32768, bias_eff f64[64] at +40960.
__global__ void snn_prep(const float* __restrict__ w1, const float* __restrict__ b1,
                         const float* __restrict__ w2, unsigned char* __restrict__ wsb) {
    int tid = threadIdx.x;
    // w1: [64][128] scale 2^34 -> A-frags (A[m=neuron][k=input])
    for (int it = tid; it < 8192; it += 256) {
        int n = it >> 7, k = it & 127;
        int V = (int)llround((double)w1[n * 128 + k] * 0x1p34);
        int nt = n >> 4, m = n & 15, kt = k >> 6, kgp = (k >> 4) & 3, e = k & 15;
        unsigned base = (unsigned)(((nt * 2 + kt) * 4) << 10) + (unsigned)(((kgp << 4) | m) * 16 + e);
#pragma unroll
        for (int p = 0; p < 4; ++p) {
            int d = ((V + 128) & 255) - 128; V = (V - d) >> 8;
            wsb[base + ((unsigned)p << 10)] = (unsigned char)d;
        }
    }
    // w2: [32][64] scale 2^33 -> B-frags (B[k=L1 neuron][n=L2 neuron])
    for (int it = tid; it < 2048; it += 256) {
        int n = it >> 6, k = it & 63;
        int V = (int)llround((double)w2[n * 64 + k] * 0x1p33);
        int nt2 = n >> 4, c = n & 15, kgp = k >> 4, e = k & 15;
        unsigned base = 32768u + (unsigned)((nt2 * 4) << 10) + (unsigned)(((kgp << 4) | c) * 16 + e);
#pragma unroll
        for (int p = 0; p < 4; ++p) {
            int d = ((V + 128) & 255) - 128; V = (V - d) >> 8;
            wsb[base + ((unsigned)p << 10)] = (unsigned char)d;
        }
    }
    // bias_eff[n] = b1[n] + 1082163328 * sum_k Vw1[n][k] * 2^-61
    if (tid < 64) {
        long long s = 0;
        for (int k = 0; k < 128; ++k) s += llround((double)w1[tid * 128 + k] * 0x1p34);
        double* biasd = (double*)(wsb + 40960);
        biasd[tid] = (double)b1[tid] + 1082163328.0 * (double)s * 0x1p-61;
    }
}

// ---------------- main fused kernel ----------------
__global__ __launch_bounds__(256, 2) void snn_main(
    const float* __restrict__ x,
    const float* __restrict__ b2,
    const float* __restrict__ w3,
    const float* __restrict__ b3,
    const unsigned char* __restrict__ wsb,
    float* __restrict__ out)
{
    // per-wave spike region: 160 srows (srow = t*16 + r) x 64 i8 = 10240B; total 40960B
    __shared__ __align__(16) unsigned char sS[4][10240];

    const int tid  = threadIdx.x;
    const int wave = tid >> 6;
    const int lane = tid & 63;
    const int m15  = lane & 15;      // P1: batch row; P2: A-row (srow) & k2 col
    const int kg   = lane >> 4;      // P1: k-group / neuron sub-block; P2: k-strip / out-row group
    const int swz  = (m15 >> 1) & 3; // dword-group bank swizzle key
    unsigned char* sw = sS[wave];
    const int r0 = blockIdx.x * 64 + wave * 16;   // this wave's first batch row

    // ---- x digit B-frags for this wave's 16 rows ----
    i32x4 bx[2][4];
#pragma unroll
    for (int kt = 0; kt < 2; ++kt) {
        const float4* xp = (const float4*)(x + (size_t)(r0 + m15) * 128 + kt * 64 + kg * 16);
        float4 q0 = xp[0], q1 = xp[1], q2 = xp[2], q3 = xp[3];
        unsigned o0[4], o1[4], o2[4], o3[4];
#pragma unroll
        for (int g = 0; g < 4; ++g) {
            float f0 = (g == 0 ? q0.x : g == 1 ? q1.x : g == 2 ? q2.x : q3.x);
            float f1 = (g == 0 ? q0.y : g == 1 ? q1.y : g == 2 ? q2.y : q3.y);
            float f2 = (g == 0 ? q0.z : g == 1 ? q1.z : g == 2 ? q2.z : q3.z);
            float f3 = (g == 0 ? q0.w : g == 1 ? q1.w : g == 2 ? q2.w : q3.w);
            unsigned V0 = ((unsigned)(__float2int_rn(f0 * 0x1p27f) + 0x40000000)) ^ 0x80808080u;
            unsigned V1 = ((unsigned)(__float2int_rn(f1 * 0x1p27f) + 0x40000000)) ^ 0x80808080u;
            unsigned V2 = ((unsigned)(__float2int_rn(f2 * 0x1p27f) + 0x40000000)) ^ 0x80808080u;
            unsigned V3 = ((unsigned)(__float2int_rn(f3 * 0x1p27f) + 0x40000000)) ^ 0x80808080u;
            unsigned A01 = prm(V1, V0, 0x05010400u), A23 = prm(V3, V2, 0x05010400u);
            unsigned B01 = prm(V1, V0, 0x07030602u), B23 = prm(V3, V2, 0x07030602u);
            o0[g] = prm(A23, A01, 0x05040100u);
            o1[g] = prm(A23, A01, 0x07060302u);
            o2[g] = prm(B23, B01, 0x05040100u);
            o3[g] = prm(B23, B01, 0x07060302u);
        }
        bx[kt][0] = (i32x4){(int)o0[0], (int)o0[1], (int)o0[2], (int)o0[3]};
        bx[kt][1] = (i32x4){(int)o1[0], (int)o1[1], (int)o1[2], (int)o1[3]};
        bx[kt][2] = (i32x4){(int)o2[0], (int)o2[1], (int)o2[2], (int)o2[3]};
        bx[kt][3] = (i32x4){(int)o3[0], (int)o3[1], (int)o3[2], (int)o3[3]};
    }

    const double* biasd = (const double*)(wsb + 40960);

    // ===== P1: 4 neuron-Mtiles; exact fc1 + fp64 LIF1 + swizzled spike writes =====
#pragma unroll
    for (int nt1 = 0; nt1 < 4; ++nt1) {
        i32x4 aw[2][4];
#pragma unroll
        for (int kt = 0; kt < 2; ++kt)
#pragma unroll
            for (int p = 0; p < 4; ++p)
                aw[kt][p] = *(const i32x4*)(wsb + (unsigned)(((nt1 * 2 + kt) * 4 + p) << 10) + lane * 16);

        i32x4 acc0 = {0,0,0,0}, acc1 = {0,0,0,0}, acc2 = {0,0,0,0}, acc3 = {0,0,0,0}, acc4 = {0,0,0,0};
#pragma unroll
        for (int kt = 0; kt < 2; ++kt) {
            // shift classes s = i(w) + j(x), s >= 2
            acc0 = __builtin_amdgcn_mfma_i32_16x16x64_i8(aw[kt][0], bx[kt][2], acc0, 0, 0, 0);
            acc0 = __builtin_amdgcn_mfma_i32_16x16x64_i8(aw[kt][1], bx[kt][1], acc0, 0, 0, 0);
            acc0 = __builtin_amdgcn_mfma_i32_16x16x64_i8(aw[kt][2], bx[kt][0], acc0, 0, 0, 0);
            acc1 = __builtin_amdgcn_mfma_i32_16x16x64_i8(aw[kt][0], bx[kt][3], acc1, 0, 0, 0);
            acc1 = __builtin_amdgcn_mfma_i32_16x16x64_i8(aw[kt][1], bx[kt][2], acc1, 0, 0, 0);
            acc1 = __builtin_amdgcn_mfma_i32_16x16x64_i8(aw[kt][2], bx[kt][1], acc1, 0, 0, 0);
            acc1 = __builtin_amdgcn_mfma_i32_16x16x64_i8(aw[kt][3], bx[kt][0], acc1, 0, 0, 0);
            acc2 = __builtin_amdgcn_mfma_i32_16x16x64_i8(aw[kt][1], bx[kt][3], acc2, 0, 0, 0);
            acc2 = __builtin_amdgcn_mfma_i32_16x16x64_i8(aw[kt][2], bx[kt][2], acc2, 0, 0, 0);
            acc2 = __builtin_amdgcn_mfma_i32_16x16x64_i8(aw[kt][3], bx[kt][1], acc2, 0, 0, 0);
            acc3 = __builtin_amdgcn_mfma_i32_16x16x64_i8(aw[kt][2], bx[kt][3], acc3, 0, 0, 0);
            acc3 = __builtin_amdgcn_mfma_i32_16x16x64_i8(aw[kt][3], bx[kt][2], acc3, 0, 0, 0);
            acc4 = __builtin_amdgcn_mfma_i32_16x16x64_i8(aw[kt][3], bx[kt][3], acc4, 0, 0, 0);
        }
        // combine classes exactly in fp64; LIF1; swizzled spike write (1 b32/step)
        double c[4], mem[4];
        bool rst[4];
#pragma unroll
        for (int j = 0; j < 4; ++j) {
            c[j] = biasd[nt1 * 16 + kg * 4 + j]
                 + (double)acc0[j] * 0x1p-45 + (double)acc1[j] * 0x1p-37
                 + (double)acc2[j] * 0x1p-29 + (double)acc3[j] * 0x1p-21
                 + (double)acc4[j] * 0x1p-13;
            mem[j] = 0.0; rst[j] = false;
        }
        const int wbase = ((nt1 ^ swz) << 4) + kg * 4;   // dword-group swizzle
#pragma unroll
        for (int t = 0; t < 10; ++t) {
            unsigned sb = 0u;
#pragma unroll
            for (int j = 0; j < 4; ++j) {
                double t2 = __fma_rn(0.9, mem[j], c[j]);
                mem[j] = rst[j] ? (t2 - 1.0) : t2;
                rst[j] = mem[j] > 1.0;
                sb |= rst[j] ? (1u << (8 * j)) : 0u;
            }
            *(unsigned*)(sw + (t * 16 + m15) * 64 + wbase) = sb;
        }
    }

    __builtin_amdgcn_sched_barrier(0);   // keep w2f loads out of P1's register peak

    // ---- w2 B-frags + P3 constants ----
    i32x4 w2f[2][4];
#pragma unroll
    for (int nt2 = 0; nt2 < 2; ++nt2)
#pragma unroll
        for (int p = 0; p < 4; ++p)
            w2f[nt2][p] = *(const i32x4*)(wsb + 32768u + (unsigned)((nt2 * 4 + p) << 10) + lane * 16);

    const double b2d0 = (double)b2[m15];
    const double b2d1 = (double)b2[m15 + 16];
    float w3lo[4], w3hi[4], b3c[4];
#pragma unroll
    for (int cc = 0; cc < 4; ++cc) {
        w3lo[cc] = w3[cc * 32 + m15];
        w3hi[cc] = w3[cc * 32 + m15 + 16];
        b3c[cc]  = (float)((double)b3[cc] * 41.381059609);   // b3 * sum(c_t)
    }

    // ===== P2: time-slice MFMAs + fp64 LIF2 fully in registers =====
    // lane owns rows r = 4*kg+j (j=0..3), k2 = m15 (s=0..3) and m15+16 (s=4..7)
    const float CTf[10] = {6.5132156f, 6.1257951f, 5.6953279f, 5.2170310f, 4.6855900f,
                           4.0951000f, 3.4390000f, 2.7100000f, 1.9000000f, 1.0000000f};
    double mem2[8] = {0,0,0,0,0,0,0,0};
    float  z[8]    = {0,0,0,0,0,0,0,0};
    bool   rs2[8]  = {false,false,false,false,false,false,false,false};

#pragma unroll
    for (int t = 0; t < 10; ++t) {
        i32x4 a = *(const i32x4*)(sw + (t * 16 + m15) * 64 + ((kg ^ swz) << 4));
#pragma unroll
        for (int nt2 = 0; nt2 < 2; ++nt2) {      // sequential nt2: halves live p-regs
            i32x4 p0 = {0,0,0,0}, p1 = {0,0,0,0}, p2 = {0,0,0,0}, p3 = {0,0,0,0};
            p0 = __builtin_amdgcn_mfma_i32_16x16x64_i8(a, w2f[nt2][0], p0, 0, 0, 0);
            p1 = __builtin_amdgcn_mfma_i32_16x16x64_i8(a, w2f[nt2][1], p1, 0, 0, 0);
            p2 = __builtin_amdgcn_mfma_i32_16x16x64_i8(a, w2f[nt2][2], p2, 0, 0, 0);
            p3 = __builtin_amdgcn_mfma_i32_16x16x64_i8(a, w2f[nt2][3], p3, 0, 0, 0);
            const double b2d = nt2 ? b2d1 : b2d0;
#pragma unroll
            for (int j = 0; j < 4; ++j) {
                const int s = nt2 * 4 + j;
                int lo = p0[j] + p1[j] * 256 + p2[j] * 65536;   // exact, |lo| < 2^30
                double cv = __fma_rn((double)lo, 0x1p-33,
                            __fma_rn((double)p3[j], 0x1p-9, b2d));
                double t2 = __fma_rn(0.9, mem2[s], cv);
                mem2[s] = rs2[s] ? (t2 - 1.0) : t2;
                rs2[s] = mem2[s] > 1.0;
                z[s] += rs2[s] ? CTf[t] : 0.0f;
            }
        }
    }

    // ===== P3: fused w3 reduce (16-lane butterflies) + store =====
#pragma unroll
    for (int j = 0; j < 4; ++j) {
        float red[4];
#pragma unroll
        for (int cc = 0; cc < 4; ++cc) {
            float v = z[j] * w3lo[cc] + z[4 + j] * w3hi[cc];
            v += __shfl_xor(v, 1);
            v += __shfl_xor(v, 2);
            v += __shfl_xor(v, 4);
            v += __shfl_xor(v, 8);
            red[cc] = (v + b3c[cc]) * 0.1f;
        }
        if (m15 == 0) {
            float4 o4 = {red[0], red[1], red[2], red[3]};
            *(float4*)(out + (size_t)(r0 + kg * 4 + j) * 4) = o4;
        }
    }
}

extern "C" void kernel_launch(void* const* d_in, const int* in_sizes, int n_in,
                              void* d_out, int out_size, void* d_ws, size_t ws_size,
                              hipStream_t stream) {
    const float* x  = (const float*)d_in[0];
    const float* w1 = (const float*)d_in[1];
    const float* b1 = (const float*)d_in[2];
    const float* w2 = (const float*)d_in[3];
    const float* b2 = (const float*)d_in[4];
    const float* w3 = (const float*)d_in[5];
    const float* b3 = (const float*)d_in[6];
    unsigned char* wsb = (unsigned char*)d_ws;   // needs 41472 bytes
    float* out = (float*)d_out;

    snn_prep<<<1, 256, 0, stream>>>(w1, b1, w2, wsb);
    snn_main<<<NBLK, 256, 0, stream>>>(x, b2, w3, b3, wsb, out);
}

// Round 10
// 109.741 us; speedup vs baseline: 4.2404x; 1.8659x over previous
//
#include <hip/hip_runtime.h>

// SNN fused kernel for MI355X (gfx950) — round 9: EXACT round-6 source (which
// passed at absmax 0.02148438) with only two changes:
//   1. __launch_bounds__(256,2) -> (256,1): removes the 128-VGPR cap that
//      caused round-6's 613MB scratch-spill traffic (hipcc empirical law:
//      VGPR cap ~= 256/arg; observed 80/64/128 at arg 3/4/2).
//   2. Hard fence between P1 and P2 (s_waitcnt lgkmcnt(0) + sched_barrier):
//      zero cost; closes the type-punned-LDS reorder license.
//
//  Round-7/8 forensics: both failed at the IDENTICAL absmax 0.0517578125
//  across different binaries => deterministic miscompile, not a race. Their
//  shared deltas vs round 6 were {arg1, per-kt awk loads, #pragma unroll 1}.
//  This round reverts the latter two (keeps round-6's fully-unrolled nt1 loop
//  and preloaded aw[2][4]) to isolate arg1 as the only variable.
//
//  Numerics (passed in rounds 2/4/5/6 at 0.02148438):
//   - V = rne(x*2^27); V' = V + 2^30 >= 0; bytes of (V'^0x80808080) are exact
//     signed digits of (V - 1082163328); constant folded into bias_eff.
//   - w1/w2 quantized at 2^34 / 2^33, balanced signed 8-bit digits.
//   - Digit-pair products accumulate EXACTLY in i32 MFMA accs; classes s=2..6
//     combined in fp64 (s<2 dropped, <5e-10). LIF recurrences fp64.
//   - Layer 3 closed form: out = (w3 . sum_t c_t*spk2_t + b3*sum(c_t))/10.
//  Structure: wave owns 16 batch rows end-to-end; spikes in per-wave 10KB LDS
//  (srow = t*16 + r, dword-group swizzle nt^((r>>1)&3)); LIF2 in registers;
//  zero __syncthreads.

#define NBLK 2048   // 2048 blocks * 64 rows = 131072

typedef __attribute__((ext_vector_type(4))) int i32x4;

__device__ __forceinline__ unsigned prm(unsigned hi, unsigned lo, unsigned sel) {
    return __builtin_amdgcn_perm(hi, lo, sel);
}

// ---------------- prep: identical to rounds 4-8 ----------------
// i8 16x16x64 frags: lane l -> (row|col) = l&15, k = (l>>4)*16 + e, e = byte 0..15.
// ws bytes: w1 A-frags [((nt*2+kt)*4+p)*1024], w2 B-frags at +32768, bias_eff f64[64] at +40960.
__global__ void snn_prep(const float* __restrict__ w1, const float* __restrict__ b1,
                         const float* __restrict__ w2, unsigned char* __restrict__ wsb) {
    int tid = threadIdx.x;
    // w1: [64][128] scale 2^34 -> A-frags (A[m=neuron][k=input])
    for (int it = tid; it < 8192; it += 256) {
        int n = it >> 7, k = it & 127;
        int V = (int)llround((double)w1[n * 128 + k] * 0x1p34);
        int nt = n >> 4, m = n & 15, kt = k >> 6, kgp = (k >> 4) & 3, e = k & 15;
        unsigned base = (unsigned)(((nt * 2 + kt) * 4) << 10) + (unsigned)(((kgp << 4) | m) * 16 + e);
#pragma unroll
        for (int p = 0; p < 4; ++p) {
            int d = ((V + 128) & 255) - 128; V = (V - d) >> 8;
            wsb[base + ((unsigned)p << 10)] = (unsigned char)d;
        }
    }
    // w2: [32][64] scale 2^33 -> B-frags (B[k=L1 neuron][n=L2 neuron])
    for (int it = tid; it < 2048; it += 256) {
        int n = it >> 6, k = it & 63;
        int V = (int)llround((double)w2[n * 64 + k] * 0x1p33);
        int nt2 = n >> 4, c = n & 15, kgp = k >> 4, e = k & 15;
        unsigned base = 32768u + (unsigned)((nt2 * 4) << 10) + (unsigned)(((kgp << 4) | c) * 16 + e);
#pragma unroll
        for (int p = 0; p < 4; ++p) {
            int d = ((V + 128) & 255) - 128; V = (V - d) >> 8;
            wsb[base + ((unsigned)p << 10)] = (unsigned char)d;
        }
    }
    // bias_eff[n] = b1[n] + 1082163328 * sum_k Vw1[n][k] * 2^-61
    if (tid < 64) {
        long long s = 0;
        for (int k = 0; k < 128; ++k) s += llround((double)w1[tid * 128 + k] * 0x1p34);
        double* biasd = (double*)(wsb + 40960);
        biasd[tid] = (double)b1[tid] + 1082163328.0 * (double)s * 0x1p-61;
    }
}

// ---------------- main fused kernel ----------------
__global__ __launch_bounds__(256, 1) void snn_main(
    const float* __restrict__ x,
    const float* __restrict__ b2,
    const float* __restrict__ w3,
    const float* __restrict__ b3,
    const unsigned char* __restrict__ wsb,
    float* __restrict__ out)
{
    // per-wave spike region: 160 srows (srow = t*16 + r) x 64 i8 = 10240B; total 40960B
    __shared__ __align__(16) unsigned char sS[4][10240];

    const int tid  = threadIdx.x;
    const int wave = tid >> 6;
    const int lane = tid & 63;
    const int m15  = lane & 15;      // P1: batch row; P2: A-row (srow) & k2 col
    const int kg   = lane >> 4;      // P1: k-group / neuron sub-block; P2: k-strip / out-row group
    const int swz  = (m15 >> 1) & 3; // dword-group bank swizzle key
    unsigned char* sw = sS[wave];
    const int r0 = blockIdx.x * 64 + wave * 16;   // this wave's first batch row

    // ---- x digit B-frags for this wave's 16 rows ----
    i32x4 bx[2][4];
#pragma unroll
    for (int kt = 0; kt < 2; ++kt) {
        const float4* xp = (const float4*)(x + (size_t)(r0 + m15) * 128 + kt * 64 + kg * 16);
        float4 q0 = xp[0], q1 = xp[1], q2 = xp[2], q3 = xp[3];
        unsigned o0[4], o1[4], o2[4], o3[4];
#pragma unroll
        for (int g = 0; g < 4; ++g) {
            float f0 = (g == 0 ? q0.x : g == 1 ? q1.x : g == 2 ? q2.x : q3.x);
            float f1 = (g == 0 ? q0.y : g == 1 ? q1.y : g == 2 ? q2.y : q3.y);
            float f2 = (g == 0 ? q0.z : g == 1 ? q1.z : g == 2 ? q2.z : q3.z);
            float f3 = (g == 0 ? q0.w : g == 1 ? q1.w : g == 2 ? q2.w : q3.w);
            unsigned V0 = ((unsigned)(__float2int_rn(f0 * 0x1p27f) + 0x40000000)) ^ 0x80808080u;
            unsigned V1 = ((unsigned)(__float2int_rn(f1 * 0x1p27f) + 0x40000000)) ^ 0x80808080u;
            unsigned V2 = ((unsigned)(__float2int_rn(f2 * 0x1p27f) + 0x40000000)) ^ 0x80808080u;
            unsigned V3 = ((unsigned)(__float2int_rn(f3 * 0x1p27f) + 0x40000000)) ^ 0x80808080u;
            unsigned A01 = prm(V1, V0, 0x05010400u), A23 = prm(V3, V2, 0x05010400u);
            unsigned B01 = prm(V1, V0, 0x07030602u), B23 = prm(V3, V2, 0x07030602u);
            o0[g] = prm(A23, A01, 0x05040100u);
            o1[g] = prm(A23, A01, 0x07060302u);
            o2[g] = prm(B23, B01, 0x05040100u);
            o3[g] = prm(B23, B01, 0x07060302u);
        }
        bx[kt][0] = (i32x4){(int)o0[0], (int)o0[1], (int)o0[2], (int)o0[3]};
        bx[kt][1] = (i32x4){(int)o1[0], (int)o1[1], (int)o1[2], (int)o1[3]};
        bx[kt][2] = (i32x4){(int)o2[0], (int)o2[1], (int)o2[2], (int)o2[3]};
        bx[kt][3] = (i32x4){(int)o3[0], (int)o3[1], (int)o3[2], (int)o3[3]};
    }

    const double* biasd = (const double*)(wsb + 40960);

    // ===== P1: 4 neuron-Mtiles; exact fc1 + fp64 LIF1 + swizzled spike writes =====
#pragma unroll
    for (int nt1 = 0; nt1 < 4; ++nt1) {
        i32x4 aw[2][4];
#pragma unroll
        for (int kt = 0; kt < 2; ++kt)
#pragma unroll
            for (int p = 0; p < 4; ++p)
                aw[kt][p] = *(const i32x4*)(wsb + (unsigned)(((nt1 * 2 + kt) * 4 + p) << 10) + lane * 16);

        i32x4 acc0 = {0,0,0,0}, acc1 = {0,0,0,0}, acc2 = {0,0,0,0}, acc3 = {0,0,0,0}, acc4 = {0,0,0,0};
#pragma unroll
        for (int kt = 0; kt < 2; ++kt) {
            // shift classes s = i(w) + j(x), s >= 2
            acc0 = __builtin_amdgcn_mfma_i32_16x16x64_i8(aw[kt][0], bx[kt][2], acc0, 0, 0, 0);
            acc0 = __builtin_amdgcn_mfma_i32_16x16x64_i8(aw[kt][1], bx[kt][1], acc0, 0, 0, 0);
            acc0 = __builtin_amdgcn_mfma_i32_16x16x64_i8(aw[kt][2], bx[kt][0], acc0, 0, 0, 0);
            acc1 = __builtin_amdgcn_mfma_i32_16x16x64_i8(aw[kt][0], bx[kt][3], acc1, 0, 0, 0);
            acc1 = __builtin_amdgcn_mfma_i32_16x16x64_i8(aw[kt][1], bx[kt][2], acc1, 0, 0, 0);
            acc1 = __builtin_amdgcn_mfma_i32_16x16x64_i8(aw[kt][2], bx[kt][1], acc1, 0, 0, 0);
            acc1 = __builtin_amdgcn_mfma_i32_16x16x64_i8(aw[kt][3], bx[kt][0], acc1, 0, 0, 0);
            acc2 = __builtin_amdgcn_mfma_i32_16x16x64_i8(aw[kt][1], bx[kt][3], acc2, 0, 0, 0);
            acc2 = __builtin_amdgcn_mfma_i32_16x16x64_i8(aw[kt][2], bx[kt][2], acc2, 0, 0, 0);
            acc2 = __builtin_amdgcn_mfma_i32_16x16x64_i8(aw[kt][3], bx[kt][1], acc2, 0, 0, 0);
            acc3 = __builtin_amdgcn_mfma_i32_16x16x64_i8(aw[kt][2], bx[kt][3], acc3, 0, 0, 0);
            acc3 = __builtin_amdgcn_mfma_i32_16x16x64_i8(aw[kt][3], bx[kt][2], acc3, 0, 0, 0);
            acc4 = __builtin_amdgcn_mfma_i32_16x16x64_i8(aw[kt][3], bx[kt][3], acc4, 0, 0, 0);
        }
        // combine classes exactly in fp64; LIF1; swizzled spike write (1 b32/step)
        double c[4], mem[4];
        bool rst[4];
#pragma unroll
        for (int j = 0; j < 4; ++j) {
            c[j] = biasd[nt1 * 16 + kg * 4 + j]
                 + (double)acc0[j] * 0x1p-45 + (double)acc1[j] * 0x1p-37
                 + (double)acc2[j] * 0x1p-29 + (double)acc3[j] * 0x1p-21
                 + (double)acc4[j] * 0x1p-13;
            mem[j] = 0.0; rst[j] = false;
        }
        const int wbase = ((nt1 ^ swz) << 4) + kg * 4;   // dword-group swizzle
#pragma unroll
        for (int t = 0; t < 10; ++t) {
            unsigned sb = 0u;
#pragma unroll
            for (int j = 0; j < 4; ++j) {
                double t2 = __fma_rn(0.9, mem[j], c[j]);
                mem[j] = rst[j] ? (t2 - 1.0) : t2;
                rst[j] = mem[j] > 1.0;
                sb |= rst[j] ? (1u << (8 * j)) : 0u;
            }
            *(unsigned*)(sw + (t * 16 + m15) * 64 + wbase) = sb;
        }
    }

    // ---- hard fence: all P1 LDS writes complete (hardware) and cannot be
    // reordered against P2's type-punned reads (compiler). Zero steady cost. ----
    asm volatile("s_waitcnt lgkmcnt(0)" ::: "memory");
    __builtin_amdgcn_sched_barrier(0);

    // ---- w2 B-frags + P3 constants ----
    i32x4 w2f[2][4];
#pragma unroll
    for (int nt2 = 0; nt2 < 2; ++nt2)
#pragma unroll
        for (int p = 0; p < 4; ++p)
            w2f[nt2][p] = *(const i32x4*)(wsb + 32768u + (unsigned)((nt2 * 4 + p) << 10) + lane * 16);

    const double b2d0 = (double)b2[m15];
    const double b2d1 = (double)b2[m15 + 16];
    float w3lo[4], w3hi[4], b3c[4];
#pragma unroll
    for (int cc = 0; cc < 4; ++cc) {
        w3lo[cc] = w3[cc * 32 + m15];
        w3hi[cc] = w3[cc * 32 + m15 + 16];
        b3c[cc]  = (float)((double)b3[cc] * 41.381059609);   // b3 * sum(c_t)
    }

    // ===== P2: time-slice MFMAs + fp64 LIF2 fully in registers =====
    // lane owns rows r = 4*kg+j (j=0..3), k2 = m15 (s=0..3) and m15+16 (s=4..7)
    const float CTf[10] = {6.5132156f, 6.1257951f, 5.6953279f, 5.2170310f, 4.6855900f,
                           4.0951000f, 3.4390000f, 2.7100000f, 1.9000000f, 1.0000000f};
    double mem2[8] = {0,0,0,0,0,0,0,0};
    float  z[8]    = {0,0,0,0,0,0,0,0};
    bool   rs2[8]  = {false,false,false,false,false,false,false,false};

#pragma unroll
    for (int t = 0; t < 10; ++t) {
        i32x4 a = *(const i32x4*)(sw + (t * 16 + m15) * 64 + ((kg ^ swz) << 4));
#pragma unroll
        for (int nt2 = 0; nt2 < 2; ++nt2) {      // sequential nt2: halves live p-regs
            i32x4 p0 = {0,0,0,0}, p1 = {0,0,0,0}, p2 = {0,0,0,0}, p3 = {0,0,0,0};
            p0 = __builtin_amdgcn_mfma_i32_16x16x64_i8(a, w2f[nt2][0], p0, 0, 0, 0);
            p1 = __builtin_amdgcn_mfma_i32_16x16x64_i8(a, w2f[nt2][1], p1, 0, 0, 0);
            p2 = __builtin_amdgcn_mfma_i32_16x16x64_i8(a, w2f[nt2][2], p2, 0, 0, 0);
            p3 = __builtin_amdgcn_mfma_i32_16x16x64_i8(a, w2f[nt2][3], p3, 0, 0, 0);
            const double b2d = nt2 ? b2d1 : b2d0;
#pragma unroll
            for (int j = 0; j < 4; ++j) {
                const int s = nt2 * 4 + j;
                int lo = p0[j] + p1[j] * 256 + p2[j] * 65536;   // exact, |lo| < 2^30
                double cv = __fma_rn((double)lo, 0x1p-33,
                            __fma_rn((double)p3[j], 0x1p-9, b2d));
                double t2 = __fma_rn(0.9, mem2[s], cv);
                mem2[s] = rs2[s] ? (t2 - 1.0) : t2;
                rs2[s] = mem2[s] > 1.0;
                z[s] += rs2[s] ? CTf[t] : 0.0f;
            }
        }
    }

    // ===== P3: fused w3 reduce (16-lane butterflies) + store =====
#pragma unroll
    for (int j = 0; j < 4; ++j) {
        float red[4];
#pragma unroll
        for (int cc = 0; cc < 4; ++cc) {
            float v = z[j] * w3lo[cc] + z[4 + j] * w3hi[cc];
            v += __shfl_xor(v, 1);
            v += __shfl_xor(v, 2);
            v += __shfl_xor(v, 4);
            v += __shfl_xor(v, 8);
            red[cc] = (v + b3c[cc]) * 0.1f;
        }
        if (m15 == 0) {
            float4 o4 = {red[0], red[1], red[2], red[3]};
            *(float4*)(out + (size_t)(r0 + kg * 4 + j) * 4) = o4;
        }
    }
}

extern "C" void kernel_launch(void* const* d_in, const int* in_sizes, int n_in,
                              void* d_out, int out_size, void* d_ws, size_t ws_size,
                              hipStream_t stream) {
    const float* x  = (const float*)d_in[0];
    const float* w1 = (const float*)d_in[1];
    const float* b1 = (const float*)d_in[2];
    const float* w2 = (const float*)d_in[3];
    const float* b2 = (const float*)d_in[4];
    const float* w3 = (const float*)d_in[5];
    const float* b3 = (const float*)d_in[6];
    unsigned char* wsb = (unsigned char*)d_ws;   // needs 41472 bytes
    float* out = (float*)d_out;

    snn_prep<<<1, 256, 0, stream>>>(w1, b1, w2, wsb);
    snn_main<<<NBLK, 256, 0, stream>>>(x, b2, w3, b3, wsb, out);
}

// Round 11
// 107.923 us; speedup vs baseline: 4.3119x; 1.0168x over previous
//
#include <hip/hip_runtime.h>

// SNN fused kernel for MI355X (gfx950) — round 10: register-liveness fences +
// 1-wave blocks to fix round-9's 1-wave/SIMD occupancy collapse.
//
//  Round-9 post-mortem: passed (absmax 0.02148438) but VGPR_Count=256,
//  Occupancy 10.5% (1 wave/SIMD), dur 100us. With launch_bounds arg=1 (cap
//  256) and fully-unrolled nt1/nt2 loops, the scheduler hoists all weight-
//  fragment loads (128+32 regs) into one live range. Fundamental state ~130.
//  Fixes (numerics byte-identical):
//   1. sched_barrier(0) between nt1 iterations — one nt1's aw[2][4] live at
//      a time (P1 body itself is round-9 verbatim; NOT the round-7 per-kt
//      refactor that miscompiled).
//   2. P2 nt2-OUTER: per-nt2 w2f[4] (16 regs), fence between passes; CT
//      weights as inline literals (same float values -> bit-identical z).
//   3. 64-thread blocks (grid 8192, 10KB LDS/block): wave-granular occupancy.
//  launch_bounds arg stays 1 — allocator caps (arg>=2) caused the round-6
//  613MB scratch-spill catastrophe; fences shrink usage without spill risk.
//
//  Numerics (passed rounds 2/4/5/6/9 at 0.02148438):
//   - V = rne(x*2^27); V' = V + 2^30 >= 0; bytes of (V'^0x80808080) are exact
//     signed digits of (V - 1082163328); constant folded into bias_eff.
//   - w1/w2 quantized at 2^34 / 2^33, balanced signed 8-bit digits.
//   - Digit-pair products accumulate EXACTLY in i32 MFMA accs; classes s=2..6
//     combined in fp64 (s<2 dropped, <5e-10). LIF recurrences fp64.
//   - Layer 3 closed form: out = (w3 . sum_t c_t*spk2_t + b3*sum(c_t))/10.

#define NBLK 8192   // 8192 blocks * 16 rows = 131072

typedef __attribute__((ext_vector_type(4))) int i32x4;

__device__ __forceinline__ unsigned prm(unsigned hi, unsigned lo, unsigned sel) {
    return __builtin_amdgcn_perm(hi, lo, sel);
}

// ---------------- prep: identical to rounds 4-9 ----------------
// i8 16x16x64 frags: lane l -> (row|col) = l&15, k = (l>>4)*16 + e, e = byte 0..15.
// ws bytes: w1 A-frags [((nt*2+kt)*4+p)*1024], w2 B-frags at +32768, bias_eff f64[64] at +40960.
__global__ void snn_prep(const float* __restrict__ w1, const float* __restrict__ b1,
                         const float* __restrict__ w2, unsigned char* __restrict__ wsb) {
    int tid = threadIdx.x;
    // w1: [64][128] scale 2^34 -> A-frags (A[m=neuron][k=input])
    for (int it = tid; it < 8192; it += 256) {
        int n = it >> 7, k = it & 127;
        int V = (int)llround((double)w1[n * 128 + k] * 0x1p34);
        int nt = n >> 4, m = n & 15, kt = k >> 6, kgp = (k >> 4) & 3, e = k & 15;
        unsigned base = (unsigned)(((nt * 2 + kt) * 4) << 10) + (unsigned)(((kgp << 4) | m) * 16 + e);
#pragma unroll
        for (int p = 0; p < 4; ++p) {
            int d = ((V + 128) & 255) - 128; V = (V - d) >> 8;
            wsb[base + ((unsigned)p << 10)] = (unsigned char)d;
        }
    }
    // w2: [32][64] scale 2^33 -> B-frags (B[k=L1 neuron][n=L2 neuron])
    for (int it = tid; it < 2048; it += 256) {
        int n = it >> 6, k = it & 63;
        int V = (int)llround((double)w2[n * 64 + k] * 0x1p33);
        int nt2 = n >> 4, c = n & 15, kgp = k >> 4, e = k & 15;
        unsigned base = 32768u + (unsigned)((nt2 * 4) << 10) + (unsigned)(((kgp << 4) | c) * 16 + e);
#pragma unroll
        for (int p = 0; p < 4; ++p) {
            int d = ((V + 128) & 255) - 128; V = (V - d) >> 8;
            wsb[base + ((unsigned)p << 10)] = (unsigned char)d;
        }
    }
    // bias_eff[n] = b1[n] + 1082163328 * sum_k Vw1[n][k] * 2^-61
    if (tid < 64) {
        long long s = 0;
        for (int k = 0; k < 128; ++k) s += llround((double)w1[tid * 128 + k] * 0x1p34);
        double* biasd = (double*)(wsb + 40960);
        biasd[tid] = (double)b1[tid] + 1082163328.0 * (double)s * 0x1p-61;
    }
}

// ---------------- main fused kernel: one wave per block ----------------
__global__ __launch_bounds__(64, 1) void snn_main(
    const float* __restrict__ x,
    const float* __restrict__ b2,
    const float* __restrict__ w3,
    const float* __restrict__ b3,
    const unsigned char* __restrict__ wsb,
    float* __restrict__ out)
{
    // spike region: 160 srows (srow = t*16 + r) x 64 i8 = 10240B
    __shared__ __align__(16) unsigned char sS[10240];

    const int lane = threadIdx.x;    // 0..63 (one wave)
    const int m15  = lane & 15;      // P1: batch row; P2: A-row & k2 col
    const int kg   = lane >> 4;      // P1: k-group / neuron sub-block; P2: out-row group
    const int swz  = (m15 >> 1) & 3; // dword-group bank swizzle key
    const int r0 = blockIdx.x * 16;  // this block's first batch row

    // ---- x digit B-frags for these 16 rows ----
    i32x4 bx[2][4];
#pragma unroll
    for (int kt = 0; kt < 2; ++kt) {
        const float4* xp = (const float4*)(x + (size_t)(r0 + m15) * 128 + kt * 64 + kg * 16);
        float4 q0 = xp[0], q1 = xp[1], q2 = xp[2], q3 = xp[3];
        unsigned o0[4], o1[4], o2[4], o3[4];
#pragma unroll
        for (int g = 0; g < 4; ++g) {
            float f0 = (g == 0 ? q0.x : g == 1 ? q1.x : g == 2 ? q2.x : q3.x);
            float f1 = (g == 0 ? q0.y : g == 1 ? q1.y : g == 2 ? q2.y : q3.y);
            float f2 = (g == 0 ? q0.z : g == 1 ? q1.z : g == 2 ? q2.z : q3.z);
            float f3 = (g == 0 ? q0.w : g == 1 ? q1.w : g == 2 ? q2.w : q3.w);
            unsigned V0 = ((unsigned)(__float2int_rn(f0 * 0x1p27f) + 0x40000000)) ^ 0x80808080u;
            unsigned V1 = ((unsigned)(__float2int_rn(f1 * 0x1p27f) + 0x40000000)) ^ 0x80808080u;
            unsigned V2 = ((unsigned)(__float2int_rn(f2 * 0x1p27f) + 0x40000000)) ^ 0x80808080u;
            unsigned V3 = ((unsigned)(__float2int_rn(f3 * 0x1p27f) + 0x40000000)) ^ 0x80808080u;
            unsigned A01 = prm(V1, V0, 0x05010400u), A23 = prm(V3, V2, 0x05010400u);
            unsigned B01 = prm(V1, V0, 0x07030602u), B23 = prm(V3, V2, 0x07030602u);
            o0[g] = prm(A23, A01, 0x05040100u);
            o1[g] = prm(A23, A01, 0x07060302u);
            o2[g] = prm(B23, B01, 0x05040100u);
            o3[g] = prm(B23, B01, 0x07060302u);
        }
        bx[kt][0] = (i32x4){(int)o0[0], (int)o0[1], (int)o0[2], (int)o0[3]};
        bx[kt][1] = (i32x4){(int)o1[0], (int)o1[1], (int)o1[2], (int)o1[3]};
        bx[kt][2] = (i32x4){(int)o2[0], (int)o2[1], (int)o2[2], (int)o2[3]};
        bx[kt][3] = (i32x4){(int)o3[0], (int)o3[1], (int)o3[2], (int)o3[3]};
    }

    const double* biasd = (const double*)(wsb + 40960);

    // ===== P1: 4 neuron-Mtiles; exact fc1 + fp64 LIF1 + swizzled spike writes =====
    // Body identical to round 9; sched_barrier(0) between iterations keeps only
    // one nt1's aw[2][4] live (blocks cross-iteration load hoisting).
#pragma unroll
    for (int nt1 = 0; nt1 < 4; ++nt1) {
        i32x4 aw[2][4];
#pragma unroll
        for (int kt = 0; kt < 2; ++kt)
#pragma unroll
            for (int p = 0; p < 4; ++p)
                aw[kt][p] = *(const i32x4*)(wsb + (unsigned)(((nt1 * 2 + kt) * 4 + p) << 10) + lane * 16);

        i32x4 acc0 = {0,0,0,0}, acc1 = {0,0,0,0}, acc2 = {0,0,0,0}, acc3 = {0,0,0,0}, acc4 = {0,0,0,0};
#pragma unroll
        for (int kt = 0; kt < 2; ++kt) {
            // shift classes s = i(w) + j(x), s >= 2
            acc0 = __builtin_amdgcn_mfma_i32_16x16x64_i8(aw[kt][0], bx[kt][2], acc0, 0, 0, 0);
            acc0 = __builtin_amdgcn_mfma_i32_16x16x64_i8(aw[kt][1], bx[kt][1], acc0, 0, 0, 0);
            acc0 = __builtin_amdgcn_mfma_i32_16x16x64_i8(aw[kt][2], bx[kt][0], acc0, 0, 0, 0);
            acc1 = __builtin_amdgcn_mfma_i32_16x16x64_i8(aw[kt][0], bx[kt][3], acc1, 0, 0, 0);
            acc1 = __builtin_amdgcn_mfma_i32_16x16x64_i8(aw[kt][1], bx[kt][2], acc1, 0, 0, 0);
            acc1 = __builtin_amdgcn_mfma_i32_16x16x64_i8(aw[kt][2], bx[kt][1], acc1, 0, 0, 0);
            acc1 = __builtin_amdgcn_mfma_i32_16x16x64_i8(aw[kt][3], bx[kt][0], acc1, 0, 0, 0);
            acc2 = __builtin_amdgcn_mfma_i32_16x16x64_i8(aw[kt][1], bx[kt][3], acc2, 0, 0, 0);
            acc2 = __builtin_amdgcn_mfma_i32_16x16x64_i8(aw[kt][2], bx[kt][2], acc2, 0, 0, 0);
            acc2 = __builtin_amdgcn_mfma_i32_16x16x64_i8(aw[kt][3], bx[kt][1], acc2, 0, 0, 0);
            acc3 = __builtin_amdgcn_mfma_i32_16x16x64_i8(aw[kt][2], bx[kt][3], acc3, 0, 0, 0);
            acc3 = __builtin_amdgcn_mfma_i32_16x16x64_i8(aw[kt][3], bx[kt][2], acc3, 0, 0, 0);
            acc4 = __builtin_amdgcn_mfma_i32_16x16x64_i8(aw[kt][3], bx[kt][3], acc4, 0, 0, 0);
        }
        // combine classes exactly in fp64; LIF1; swizzled spike write (1 b32/step)
        double c[4], mem[4];
        bool rst[4];
#pragma unroll
        for (int j = 0; j < 4; ++j) {
            c[j] = biasd[nt1 * 16 + kg * 4 + j]
                 + (double)acc0[j] * 0x1p-45 + (double)acc1[j] * 0x1p-37
                 + (double)acc2[j] * 0x1p-29 + (double)acc3[j] * 0x1p-21
                 + (double)acc4[j] * 0x1p-13;
            mem[j] = 0.0; rst[j] = false;
        }
        const int wbase = ((nt1 ^ swz) << 4) + kg * 4;   // dword-group swizzle
#pragma unroll
        for (int t = 0; t < 10; ++t) {
            unsigned sb = 0u;
#pragma unroll
            for (int j = 0; j < 4; ++j) {
                double t2 = __fma_rn(0.9, mem[j], c[j]);
                mem[j] = rst[j] ? (t2 - 1.0) : t2;
                rst[j] = mem[j] > 1.0;
                sb |= rst[j] ? (1u << (8 * j)) : 0u;
            }
            *(unsigned*)(sS + (t * 16 + m15) * 64 + wbase) = sb;
        }
        __builtin_amdgcn_sched_barrier(0);   // liveness fence between Mtiles
    }

    // ---- hard fence: all P1 LDS writes complete before P2's punned reads ----
    asm volatile("s_waitcnt lgkmcnt(0)" ::: "memory");
    __builtin_amdgcn_sched_barrier(0);

    // ---- P2/P3 constants ----
    const double b2d0 = (double)b2[m15];
    const double b2d1 = (double)b2[m15 + 16];
    float w3lo[4], w3hi[4], b3c[4];
#pragma unroll
    for (int cc = 0; cc < 4; ++cc) {
        w3lo[cc] = w3[cc * 32 + m15];
        w3hi[cc] = w3[cc * 32 + m15 + 16];
        b3c[cc]  = (float)((double)b3[cc] * 41.381059609);   // b3 * sum(c_t)
    }

    // ===== P2: nt2-OUTER time-slice MFMAs + fp64 LIF2 in registers =====
    // lane owns rows r = 4*kg+j (j=0..3), k2 = m15 (nt2=0) and m15+16 (nt2=1)
    float z[8] = {0,0,0,0,0,0,0,0};
#pragma unroll
    for (int nt2 = 0; nt2 < 2; ++nt2) {
        i32x4 w2f[4];
#pragma unroll
        for (int p = 0; p < 4; ++p)
            w2f[p] = *(const i32x4*)(wsb + 32768u + (unsigned)((nt2 * 4 + p) << 10) + lane * 16);
        const double b2d = nt2 ? b2d1 : b2d0;
        double mem2[4] = {0,0,0,0};
        bool rs2[4] = {false,false,false,false};
#pragma unroll
        for (int t = 0; t < 10; ++t) {
            i32x4 a = *(const i32x4*)(sS + (t * 16 + m15) * 64 + ((kg ^ swz) << 4));
            i32x4 p0 = {0,0,0,0}, p1 = {0,0,0,0}, p2 = {0,0,0,0}, p3 = {0,0,0,0};
            p0 = __builtin_amdgcn_mfma_i32_16x16x64_i8(a, w2f[0], p0, 0, 0, 0);
            p1 = __builtin_amdgcn_mfma_i32_16x16x64_i8(a, w2f[1], p1, 0, 0, 0);
            p2 = __builtin_amdgcn_mfma_i32_16x16x64_i8(a, w2f[2], p2, 0, 0, 0);
            p3 = __builtin_amdgcn_mfma_i32_16x16x64_i8(a, w2f[3], p3, 0, 0, 0);
            // c_t = (1 - 0.9^(10-t))/0.1, same float literals as round 9
            const float CTt = (t == 0) ? 6.5132156f : (t == 1) ? 6.1257951f :
                              (t == 2) ? 5.6953279f : (t == 3) ? 5.2170310f :
                              (t == 4) ? 4.6855900f : (t == 5) ? 4.0951000f :
                              (t == 6) ? 3.4390000f : (t == 7) ? 2.7100000f :
                              (t == 8) ? 1.9000000f : 1.0f;
#pragma unroll
            for (int j = 0; j < 4; ++j) {
                int lo = p0[j] + p1[j] * 256 + p2[j] * 65536;   // exact, |lo| < 2^30
                double cv = __fma_rn((double)lo, 0x1p-33,
                            __fma_rn((double)p3[j], 0x1p-9, b2d));
                double t2 = __fma_rn(0.9, mem2[j], cv);
                mem2[j] = rs2[j] ? (t2 - 1.0) : t2;
                rs2[j] = mem2[j] > 1.0;
                z[nt2 * 4 + j] += rs2[j] ? CTt : 0.0f;
            }
        }
        __builtin_amdgcn_sched_barrier(0);   // liveness fence between nt2 passes
    }

    // ===== P3: fused w3 reduce (16-lane butterflies) + store =====
#pragma unroll
    for (int j = 0; j < 4; ++j) {
        float red[4];
#pragma unroll
        for (int cc = 0; cc < 4; ++cc) {
            float v = z[j] * w3lo[cc] + z[4 + j] * w3hi[cc];
            v += __shfl_xor(v, 1);
            v += __shfl_xor(v, 2);
            v += __shfl_xor(v, 4);
            v += __shfl_xor(v, 8);
            red[cc] = (v + b3c[cc]) * 0.1f;
        }
        if (m15 == 0) {
            float4 o4 = {red[0], red[1], red[2], red[3]};
            *(float4*)(out + (size_t)(r0 + kg * 4 + j) * 4) = o4;
        }
    }
}

extern "C" void kernel_launch(void* const* d_in, const int* in_sizes, int n_in,
                              void* d_out, int out_size, void* d_ws, size_t ws_size,
                              hipStream_t stream) {
    const float* x  = (const float*)d_in[0];
    const float* w1 = (const float*)d_in[1];
    const float* b1 = (const float*)d_in[2];
    const float* w2 = (const float*)d_in[3];
    const float* b2 = (const float*)d_in[4];
    const float* w3 = (const float*)d_in[5];
    const float* b3 = (const float*)d_in[6];
    unsigned char* wsb = (unsigned char*)d_ws;   // needs 41472 bytes
    float* out = (float*)d_out;

    snn_prep<<<1, 256, 0, stream>>>(w1, b1, w2, wsb);
    snn_main<<<NBLK, 64, 0, stream>>>(x, b2, w3, b3, wsb, out);
}